// Round 1
// baseline (186.719 us; speedup 1.0000x reference)
//
#include <hip/hip_runtime.h>
#include <hip/hip_bf16.h>

// Problem geometry
#define E_CNT  256
#define D_IN   15
#define HDIM   128
#define BATCH  8192
#define ROWSPG 512                 // batch rows per workgroup
#define NRG    (BATCH / ROWSPG)    // 16 row-groups
#define NCHUNK (ROWSPG / 32)       // 16 chunks of 32 rows per WG
#define S2     136                 // LDS row stride in bf16 units (272 B, 16B-aligned)

typedef float f32x16 __attribute__((ext_vector_type(16)));
typedef short bf16x8 __attribute__((ext_vector_type(8)));
typedef short short4v __attribute__((ext_vector_type(4)));

#define MFMA(a, b, c) __builtin_amdgcn_mfma_f32_32x32x16_bf16((a), (b), (c), 0, 0, 0)

static __device__ inline short f2bf(float f) {
    __hip_bfloat16 h = __float2bfloat16(f);
    return __builtin_bit_cast(short, h);
}

static __device__ inline float sigmoid_fast(float z) {
    // 1/(1+exp(-z)) via v_exp_f32 (2^x) + v_rcp_f32. Handles +-inf limits correctly.
    float e = __builtin_amdgcn_exp2f(z * -1.44269504088896341f);
    return __builtin_amdgcn_rcpf(1.0f + e);
}

static __device__ inline f32x16 zero16() {
    f32x16 z;
#pragma unroll
    for (int i = 0; i < 16; ++i) z[i] = 0.0f;
    return z;
}

// Transposed-orientation MFMA MLP:
//   L1: h1^T[h][b]  = mfma(W1T_frag, xT_frag)          (K=16: 15 inputs + bias slot)
//   L2: h2^T[ho][b] = mfma(W2T_frag, h1T_frag) (8 K-steps) + bias MFMA step
//   L3: out^T[0][b] = mfma(W3T_frag, h2T_frag) (8 K-steps), + b3 at store
// C layout (32x32): col = lane&31 (batch), row = (reg&3) + 8*(reg>>2) + 4*(lane>>5)
// A/B frag: non-K index = lane&31, k = (lane>>5)*8 + elem
__global__ __launch_bounds__(256, 2)
void mlp256_kernel(const float* __restrict__ x,
                   const float* __restrict__ W1, const float* __restrict__ b1,
                   const float* __restrict__ W2, const float* __restrict__ b2,
                   const float* __restrict__ W3, const float* __restrict__ b3,
                   float* __restrict__ out)
{
    __shared__ __align__(16) unsigned short w2t[HDIM * S2];      // W2^T as bf16: [h_out][h_in]
    __shared__ __align__(16) unsigned short h1w[4 * 32 * S2];    // per-wave [b][h] activation buffer

    const int tid  = threadIdx.x;
    const int wave = tid >> 6;
    const int lane = tid & 63;
    const int l31  = lane & 31;
    const int hi   = lane >> 5;

    const int gid = blockIdx.x;
    const int e   = gid >> 4;          // 16 consecutive blocks share one expert (L2 reuse)
    const int rg  = gid & 15;
    const int rowbase = rg * ROWSPG;

    const float* w1p = W1 + e * (D_IN * HDIM);
    const float* b1p = b1 + e * HDIM;
    const float* w2p = W2 + e * (HDIM * HDIM);
    const float* b2p = b2 + e * HDIM;
    const float* w3p = W3 + e * HDIM;
    const float  b3v = b3[e];

    // ---- stage W2^T into LDS as bf16 (coalesced global reads, scattered b16 writes) ----
    for (int i = tid; i < HDIM * HDIM; i += 256) {
        int k = i >> 7;      // h_in
        int h = i & 127;     // h_out
        w2t[h * S2 + k] = (unsigned short)f2bf(w2p[i]);
    }

    // ---- persistent per-wave register fragments ----
    // W1A[mf]: A-frag rows h = mf*32 + l31; k = hi*8+j; slot k==15 carries b1 (x slot = 1.0)
    bf16x8 W1A[4];
#pragma unroll
    for (int mf = 0; mf < 4; ++mf) {
        int h = mf * 32 + l31;
#pragma unroll
        for (int j = 0; j < 8; ++j) {
            int k = hi * 8 + j;
            float v = (k < D_IN) ? w1p[k * HDIM + h] : b1p[h];
            W1A[mf][j] = f2bf(v);
        }
    }
    // b2 bias as an extra K-step: A holds b2[h] at k'==0, B holds 1.0 at k'==0
    bf16x8 B2A[4];
#pragma unroll
    for (int mf = 0; mf < 4; ++mf) {
#pragma unroll
        for (int j = 0; j < 8; ++j) B2A[mf][j] = 0;
        if (hi == 0) B2A[mf][0] = f2bf(b2p[mf * 32 + l31]);
    }
    bf16x8 ONEB;
#pragma unroll
    for (int j = 0; j < 8; ++j) ONEB[j] = 0;
    if (hi == 0) ONEB[0] = f2bf(1.0f);
    // W3A[ks]: A-frag with only row o==0 (lanes l31==0) nonzero
    bf16x8 W3A[8];
#pragma unroll
    for (int ks = 0; ks < 8; ++ks) {
#pragma unroll
        for (int j = 0; j < 8; ++j) W3A[ks][j] = 0;
        if (l31 == 0) {
#pragma unroll
            for (int j = 0; j < 8; ++j)
                W3A[ks][j] = f2bf(w3p[ks * 16 + hi * 8 + j]);
        }
    }

    __syncthreads();   // w2t ready; waves are independent from here on

    unsigned short* h1p = h1w + wave * (32 * S2);

    for (int c = wave; c < NCHUNK; c += 4) {
        const int r0 = rowbase + c * 32;
        const int bb = r0 + l31;

        // x B-frag: col b = l31, k = hi*8+j; slot k==15 = 1.0 (bias partner)
        bf16x8 XB;
        {
            const float* xp = x + bb * D_IN;
#pragma unroll
            for (int j = 0; j < 8; ++j) {
                int k = hi * 8 + j;
                float v = (k < D_IN) ? xp[k] : 1.0f;
                XB[j] = f2bf(v);
            }
        }

        // ---- layer 1 ----
        f32x16 acc1[4];
#pragma unroll
        for (int mf = 0; mf < 4; ++mf)
            acc1[mf] = MFMA(W1A[mf], XB, zero16());

        // sigmoid + pack to LDS [b][h] (4-consecutive-row runs per reg quad -> b64 stores)
#pragma unroll
        for (int mf = 0; mf < 4; ++mf) {
#pragma unroll
            for (int q = 0; q < 4; ++q) {
                short4v p;
                p[0] = f2bf(sigmoid_fast(acc1[mf][4 * q + 0]));
                p[1] = f2bf(sigmoid_fast(acc1[mf][4 * q + 1]));
                p[2] = f2bf(sigmoid_fast(acc1[mf][4 * q + 2]));
                p[3] = f2bf(sigmoid_fast(acc1[mf][4 * q + 3]));
                *reinterpret_cast<short4v*>(h1p + l31 * S2 + mf * 32 + q * 8 + hi * 4) = p;
            }
        }

        // ---- layer 2 ----
        f32x16 acc2[4];
#pragma unroll
        for (int mf = 0; mf < 4; ++mf) acc2[mf] = zero16();
#pragma unroll
        for (int ks = 0; ks < 8; ++ks) {
            bf16x8 hb = *reinterpret_cast<const bf16x8*>(h1p + l31 * S2 + ks * 16 + hi * 8);
#pragma unroll
            for (int mf = 0; mf < 4; ++mf) {
                bf16x8 wa = *reinterpret_cast<const bf16x8*>(w2t + (mf * 32 + l31) * S2 + ks * 16 + hi * 8);
                acc2[mf] = MFMA(wa, hb, acc2[mf]);
            }
        }
#pragma unroll
        for (int mf = 0; mf < 4; ++mf)
            acc2[mf] = MFMA(B2A[mf], ONEB, acc2[mf]);

        // sigmoid + pack h2 into the same per-wave buffer (reads above complete first)
#pragma unroll
        for (int mf = 0; mf < 4; ++mf) {
#pragma unroll
            for (int q = 0; q < 4; ++q) {
                short4v p;
                p[0] = f2bf(sigmoid_fast(acc2[mf][4 * q + 0]));
                p[1] = f2bf(sigmoid_fast(acc2[mf][4 * q + 1]));
                p[2] = f2bf(sigmoid_fast(acc2[mf][4 * q + 2]));
                p[3] = f2bf(sigmoid_fast(acc2[mf][4 * q + 3]));
                *reinterpret_cast<short4v*>(h1p + l31 * S2 + mf * 32 + q * 8 + hi * 4) = p;
            }
        }

        // ---- layer 3 ----
        f32x16 acc3 = zero16();
#pragma unroll
        for (int ks = 0; ks < 8; ++ks) {
            bf16x8 hb = *reinterpret_cast<const bf16x8*>(h1p + l31 * S2 + ks * 16 + hi * 8);
            acc3 = MFMA(W3A[ks], hb, acc3);
        }
        // out[b][e]: row 0 lives in reg 0 of hi==0 lanes
        if (lane < 32) {
            out[(size_t)(r0 + l31) * E_CNT + e] = acc3[0] + b3v;
        }
    }
}

extern "C" void kernel_launch(void* const* d_in, const int* in_sizes, int n_in,
                              void* d_out, int out_size, void* d_ws, size_t ws_size,
                              hipStream_t stream) {
    const float* x  = (const float*)d_in[0];
    const float* W1 = (const float*)d_in[1];
    const float* b1 = (const float*)d_in[2];
    const float* W2 = (const float*)d_in[3];
    const float* b2 = (const float*)d_in[4];
    const float* W3 = (const float*)d_in[5];
    const float* b3 = (const float*)d_in[6];
    float* out = (float*)d_out;

    mlp256_kernel<<<dim3(E_CNT * NRG), dim3(256), 0, stream>>>(
        x, W1, b1, W2, b2, W3, b3, out);
}